// Round 14
// baseline (22751.990 us; speedup 1.0000x reference)
//
#include <hip/hip_runtime.h>
#include <hip/hip_fp16.h>

#define B_   256
#define T_   512
#define D_   200
#define H_   320
#define L_   3
#define G3_  960
#define BH_  (B_*H_)
#define BTH_ (B_*T_*H_)

#define NSL   16             // batch row-slices of 16 rows
#define RPS   16             // rows per slice
#define NBLK  (L_*NSL)       // 48 blocks: bid = l*16 + s
#define NTHR  1024           // 16 waves
#define NTILE 60             // 16-col tiles per layer
#define KSTEP 20             // kk slots per tile: [0,10) ih, [10,20) hh
#define KHH   10
#define ASTR  656            // a_lds row stride (halves): 1312B, 16B-aligned
#define ZSTR  968
#define HSTR  328

typedef _Float16 half8 __attribute__((ext_vector_type(8)));
typedef _Float16 half4 __attribute__((ext_vector_type(4)));
typedef float    f32x4 __attribute__((ext_vector_type(4)));

// ---- ws layout (float units) ----
#define OFF_PACK  0
#define SZ_PACK_F (L_*NTILE*KSTEP*512/2)        // 921600 floats (1.84M halves)
#define OFF_STF   (OFF_PACK + SZ_PACK_F)
#define SZ_STF_F  (NSL*2*2*RPS*H_/2)            // 163840 floats
#define OFF_FLG   (OFF_STF + SZ_STF_F)
#define FLG_WORDS 4096

__device__ __forceinline__ float sigmoidf_(float v) {
    return 1.0f / (1.0f + __expf(-v));
}

__device__ __forceinline__ float wredsum(float v) {
#pragma unroll
    for (int m = 32; m > 0; m >>= 1) v += __shfl_xor(v, m, 64);
    return v;
}

__device__ __forceinline__ unsigned aload(const unsigned* p) {
    return __hip_atomic_load(p, __ATOMIC_RELAXED, __HIP_MEMORY_SCOPE_AGENT);
}
__device__ __forceinline__ void stc(unsigned* p, unsigned v) {
    __hip_atomic_store(p, v, __ATOMIC_RELAXED, __HIP_MEMORY_SCOPE_AGENT);
}

// ---------------- one-time weight repack into MFMA fragment order ----------
// wpack halves index: ((l*60+ct)*20 + kk)*512 + lane*8 + j
// lane=(grp<<4)|nr holds B[col=ct*16+nr][k=kk*32+grp*8+j]; kk<10 = ih, >=10 = hh
__global__ void k_pack(const float* __restrict__ wih0,
                       const float* __restrict__ wihr,
                       const float* __restrict__ whh,
                       float* __restrict__ ws) {
    _Float16* wp = (_Float16*)(ws + OFF_PACK);
    const int l = blockIdx.x / NTILE, ct = blockIdx.x % NTILE;
    for (int e = threadIdx.x; e < KSTEP*512; e += 256) {
        int kk = e >> 9, rem = e & 511;
        int lane = rem >> 3, j = rem & 7;
        int nr = lane & 15, grp = lane >> 4;
        int col = ct*16 + nr;
        float v = 0.f;
        if (kk < KHH) {
            int k = kk*32 + grp*8 + j;
            if (l == 0) { if (k < D_) v = wih0[(size_t)col*D_ + k]; }
            else if (k < H_) v = wihr[((size_t)(l-1)*G3_ + col)*H_ + k];
        } else {
            int k = (kk-KHH)*32 + grp*8 + j;
            if (k < H_) v = whh[((size_t)l*G3_ + col)*H_ + k];
        }
        wp[(size_t)blockIdx.x*KSTEP*512 + e] = (_Float16)v;
    }
}

__global__ void k_init(float* __restrict__ ws) {
    unsigned* flg = (unsigned*)(ws + OFF_FLG);
    int gt = blockIdx.x*blockDim.x + threadIdx.x;
    if (gt < FLG_WORDS) flg[gt] = 0u;
}

// ---------------- GEMM: NT col-tiles for this wave, accumulate in regs -----
template<int NT, int KIS>
__device__ __forceinline__ void gemm_tiles(int nr, int grp,
        const _Float16* __restrict__ wbase,
        const _Float16 (*a_lds)[ASTR],
        f32x4* accI, f32x4* accH, const int* ctj)
{
#pragma unroll
    for (int j = 0; j < NT; ++j) {
#pragma unroll
        for (int r = 0; r < 4; ++r) { accI[j][r] = 0.f; accH[j][r] = 0.f; }
    }
#pragma unroll
    for (int kk = 0; kk < KIS; ++kk) {
        half8 a = *(const half8*)&a_lds[nr][kk*32 + grp*8];
#pragma unroll
        for (int j = 0; j < NT; ++j) {
            half8 b = *(const half8*)(wbase + (size_t)(ctj[j]*KSTEP + kk)*512);
            accI[j] = __builtin_amdgcn_mfma_f32_16x16x32_f16(a, b, accI[j], 0,0,0);
        }
    }
#pragma unroll
    for (int kk = 0; kk < KHH; ++kk) {
        half8 a = *(const half8*)&a_lds[nr][320 + kk*32 + grp*8];
#pragma unroll
        for (int j = 0; j < NT; ++j) {
            half8 b = *(const half8*)(wbase + (size_t)(ctj[j]*KSTEP + KHH + kk)*512);
            accH[j] = __builtin_amdgcn_mfma_f32_16x16x32_f16(a, b, accH[j], 0,0,0);
        }
    }
}

// write this lane's acc rows for sub-phase (sub=0: rows 0-7, sub=1: rows 8-15)
template<int NT>
__device__ __forceinline__ void write_z(int nr, int grp, int sub,
        const f32x4* accI, const f32x4* accH, const int* ctj,
        const float* bi, const float* bh,
        float (*z_lds)[ZSTR], float (*hn_lds)[HSTR])
{
    if ((grp >> 1) != sub) return;
#pragma unroll
    for (int j = 0; j < NT; ++j) {
        const int col = ctj[j]*16 + nr;
        const bool ru = (col < 2*H_);
#pragma unroll
        for (int r = 0; r < 4; ++r) {
            const int m = (grp & 1)*4 + r;
            if (ru) {
                z_lds[m][col] = accI[j][r] + accH[j][r] + bi[j] + bh[j];
            } else {
                z_lds[m][col] = accI[j][r] + bi[j];
                hn_lds[m][col - 2*H_] = accH[j][r] + bh[j];
            }
        }
    }
}

// LN + gate math + h update for one row (wave w <-> global row rowbase+w)
__device__ __forceinline__ void ln_update_row(int l, int b2, int lane, int t, int rl,
        const float (*z_lds)[ZSTR], const float (*hn_lds)[HSTR],
        const float* __restrict__ lng, const float* __restrict__ lnb,
        float* hreg, _Float16 (*a_lds)[ASTR], int w,
        _Float16* stf_out, float* __restrict__ out)
{
    float zr[5], zu[5], zn[5], hn[5];
#pragma unroll
    for (int i = 0; i < 5; ++i) {
        const int j = lane + i*64;
        zr[i] = z_lds[rl][j];
        zu[i] = z_lds[rl][320 + j];
        zn[i] = z_lds[rl][640 + j];
        hn[i] = hn_lds[rl][j];
    }
    const float inv320 = 1.0f/320.0f;
    const float* g0 = &lng[(l*3+0)*H_]; const float* c0 = &lnb[(l*3+0)*H_];
    const float* g1 = &lng[(l*3+1)*H_]; const float* c1 = &lnb[(l*3+1)*H_];
    const float* g2 = &lng[(l*3+2)*H_]; const float* c2 = &lnb[(l*3+2)*H_];

    float s  = zr[0]+zr[1]+zr[2]+zr[3]+zr[4];
    float mu = wredsum(s) * inv320;
    float vs = 0.f;
#pragma unroll
    for (int i = 0; i < 5; ++i) { float d = zr[i]-mu; vs += d*d; }
    float inv = rsqrtf(wredsum(vs)*inv320 + 1e-5f);
    float r[5];
#pragma unroll
    for (int i = 0; i < 5; ++i) {
        const int j = lane + i*64;
        r[i] = sigmoidf_((zr[i]-mu)*inv * g0[j] + c0[j]);
    }
    s  = zu[0]+zu[1]+zu[2]+zu[3]+zu[4];
    mu = wredsum(s) * inv320;
    vs = 0.f;
#pragma unroll
    for (int i = 0; i < 5; ++i) { float d = zu[i]-mu; vs += d*d; }
    inv = rsqrtf(wredsum(vs)*inv320 + 1e-5f);
    float u[5];
#pragma unroll
    for (int i = 0; i < 5; ++i) {
        const int j = lane + i*64;
        u[i] = sigmoidf_((zu[i]-mu)*inv * g1[j] + c1[j]);
    }
    float z2[5];
#pragma unroll
    for (int i = 0; i < 5; ++i) z2[i] = zn[i] + r[i]*hn[i];
    s  = z2[0]+z2[1]+z2[2]+z2[3]+z2[4];
    mu = wredsum(s) * inv320;
    vs = 0.f;
#pragma unroll
    for (int i = 0; i < 5; ++i) { float d = z2[i]-mu; vs += d*d; }
    inv = rsqrtf(wredsum(vs)*inv320 + 1e-5f);
#pragma unroll
    for (int i = 0; i < 5; ++i) {
        const int j = lane + i*64;
        float nv = tanhf((z2[i]-mu)*inv * g2[j] + c2[j]);
        float hv = (1.0f - u[i])*nv + u[i]*hreg[i];
        hreg[i] = hv;
        a_lds[w][320 + j] = (_Float16)hv;            // own-h f16 for next GEMM
        if (l < 2) {                                  // coherent handoff to l+1
            unsigned hb = (unsigned)__builtin_bit_cast(unsigned short, (_Float16)hv);
            unsigned ob = (unsigned)__shfl_xor((int)hb, 1, 64);
            if ((lane & 1) == 0)
                stc((unsigned*)stf_out + (w*H_ + j)/2, (hb & 0xffffu) | (ob << 16));
        }
        if (l == 2)     out[((size_t)b2*T_ + t)*H_ + j] = hv;
        if (t == T_-1)  out[(size_t)BTH_ + ((size_t)l*B_ + b2)*H_ + j] = hv;
    }
}

// ================= persistent layer-pipeline kernel (plain launch) ==========
// Block (s,l): 16 batch rows x all 960 cols x LN x update. z/hn/h block-local
// (LDS+regs). Only cross-block traffic: 10KB h handoff (s,l)->(s,l+1) per t,
// guarded by fwd flag + ack backpressure (parity double buffer).
__launch_bounds__(NTHR, 4)
__global__ void gru_pipe(const float* __restrict__ x,
                         const float* __restrict__ h0,
                         const float* __restrict__ rmean,
                         const float* __restrict__ rvar,
                         const float* __restrict__ bih,
                         const float* __restrict__ bhh,
                         const float* __restrict__ lng,
                         const float* __restrict__ lnb,
                         float* __restrict__ out,
                         float* __restrict__ ws)
{
    const int bid = blockIdx.x;
    const int l = bid >> 4, s = bid & 15;
    const int tid = threadIdx.x;
    const int w = tid >> 6, lane = tid & 63;
    const int nr = lane & 15, grp = lane >> 4;
    const int rowbase = s * RPS;

    _Float16* wpack = (_Float16*)(ws + OFF_PACK);
    _Float16* stf   = (_Float16*)(ws + OFF_STF);
    unsigned* flg   = (unsigned*)(ws + OFF_FLG);

    __shared__ _Float16 a_lds[RPS][ASTR];   // 20992 B: [0,320) ih, [320,640) own-h
    __shared__ float    z_lds[8][ZSTR];     // 30976 B (half the rows at a time)
    __shared__ float    hn_lds[8][HSTR];    // 10496 B          -> total 62464 B

    // ---- init LDS (zero incl. pads), own-h from h0 ----
    for (int e = tid; e < RPS*ASTR; e += NTHR) ((_Float16*)a_lds)[e] = (_Float16)0.f;
    __syncthreads();
    for (int e = tid; e < RPS*H_; e += NTHR) {
        int row = e / H_, j = e - row*H_;
        a_lds[row][320 + j] = (_Float16)h0[((size_t)l*B_ + rowbase + row)*H_ + j];
    }
    float hreg[5];
#pragma unroll
    for (int i = 0; i < 5; ++i)
        hreg[i] = h0[((size_t)l*B_ + rowbase + w)*H_ + lane + i*64];
    __syncthreads();

    const int NTmine = (w < 12) ? 4 : 3;
    int ctj[4]; float bi[4], bh[4];
#pragma unroll
    for (int j = 0; j < 4; ++j) {
        int ct = w + 16*j; if (ct >= NTILE) ct = w;    // dummy (unused for NT=3)
        ctj[j] = ct;
        bi[j] = bih[l*G3_ + ct*16 + nr];
        bh[j] = bhh[l*G3_ + ct*16 + nr];
    }
    const _Float16* wbase = wpack + (size_t)l*NTILE*KSTEP*512 + lane*8;

    unsigned* fwd_src = flg + (s*2 + (l-1))*32;          // valid l>0
    unsigned* fwd_own = flg + (s*2 + l)*32;              // valid l<2
    unsigned* ack_src = flg + 2048 + (s*2 + l)*32;       // consumer (l+1)'s ack
    unsigned* ack_own = flg + 2048 + (s*2 + (l-1))*32;   // this block's ack (l>0)

    const _Float16* stf_in_base  = stf + (size_t)(s*2 + (l-1))*2*RPS*H_;
    _Float16*       stf_out_base = stf + (size_t)(s*2 + l)*2*RPS*H_;

    for (int t = 0; t < T_; ++t) {
        // ---- waits: fwd (h^{l-1}[t] ready), ack (stf slot free) ----
        if (tid == 0) {
            if (l > 0)
                while ((int)(aload(fwd_src) - (unsigned)(t+1)) < 0)
                    __builtin_amdgcn_s_sleep(1);
            if (l < 2 && t >= 2)
                while ((int)(aload(ack_src) - (unsigned)(t-1)) < 0)
                    __builtin_amdgcn_s_sleep(1);
        }
        __syncthreads();

        // ---- stage ih input into a_lds[0..KIP) ----
        if (l == 0) {
            if (tid < RPS*50) {
                int row = tid / 50, c4 = tid - row*50;
                int k = c4*4;
                float4 xv = *(const float4*)&x[((size_t)(rowbase+row)*T_ + t)*D_ + k];
                float4 mv = *(const float4*)&rmean[k];
                float4 vv = *(const float4*)&rvar[k];
                half4 h4;
                h4[0] = (_Float16)fminf(fmaxf((xv.x - mv.x)*rsqrtf(vv.x + 1e-8f), -10.f), 10.f);
                h4[1] = (_Float16)fminf(fmaxf((xv.y - mv.y)*rsqrtf(vv.y + 1e-8f), -10.f), 10.f);
                h4[2] = (_Float16)fminf(fmaxf((xv.z - mv.z)*rsqrtf(vv.z + 1e-8f), -10.f), 10.f);
                h4[3] = (_Float16)fminf(fmaxf((xv.w - mv.w)*rsqrtf(vv.w + 1e-8f), -10.f), 10.f);
                *(half4*)&a_lds[row][k] = h4;
            }
        } else {
            if (tid < RPS*40) {
                int row = tid / 40, q = tid - row*40;
                const _Float16* p = stf_in_base + (size_t)(t&1)*RPS*H_ + row*H_ + q*8;
                f32x4 v;
                asm volatile("global_load_dwordx4 %0, %1, off sc0 sc1"
                             : "=&v"(v) : "v"(p));
                asm volatile("s_waitcnt vmcnt(0)" ::: "memory");
                *(half8*)&a_lds[row][q*8] = __builtin_bit_cast(half8, v);
            }
        }
        __syncthreads();
        if (l > 0 && tid == 0) stc(ack_own, (unsigned)(t+1));   // slot consumed

        // ---- GEMM (acc in registers) ----
        f32x4 accI[4], accH[4];
        if (l == 0) {
            if (NTmine == 4) gemm_tiles<4,7 >(nr, grp, wbase, a_lds, accI, accH, ctj);
            else             gemm_tiles<3,7 >(nr, grp, wbase, a_lds, accI, accH, ctj);
        } else {
            if (NTmine == 4) gemm_tiles<4,10>(nr, grp, wbase, a_lds, accI, accH, ctj);
            else             gemm_tiles<3,10>(nr, grp, wbase, a_lds, accI, accH, ctj);
        }

        _Float16* stf_out = stf_out_base + (size_t)(t&1)*RPS*H_;

        // ---- sub-phase 0: rows 0-7 ----
        if (NTmine == 4) write_z<4>(nr, grp, 0, accI, accH, ctj, bi, bh, z_lds, hn_lds);
        else             write_z<3>(nr, grp, 0, accI, accH, ctj, bi, bh, z_lds, hn_lds);
        __syncthreads();
        if (w < 8)
            ln_update_row(l, rowbase + w, lane, t, w, z_lds, hn_lds,
                          lng, lnb, hreg, a_lds, w, stf_out, out);
        __syncthreads();
        // ---- sub-phase 1: rows 8-15 ----
        if (NTmine == 4) write_z<4>(nr, grp, 1, accI, accH, ctj, bi, bh, z_lds, hn_lds);
        else             write_z<3>(nr, grp, 1, accI, accH, ctj, bi, bh, z_lds, hn_lds);
        __syncthreads();
        if (w >= 8)
            ln_update_row(l, rowbase + w, lane, t, w - 8, z_lds, hn_lds,
                          lng, lnb, hreg, a_lds, w, stf_out, out);
        __syncthreads();                                  // drains stf stores
        if (l < 2 && tid == 0) stc(fwd_own, (unsigned)(t+1));
    }
}

extern "C" void kernel_launch(void* const* d_in, const int* in_sizes, int n_in,
                              void* d_out, int out_size, void* d_ws, size_t ws_size,
                              hipStream_t stream) {
    (void)in_sizes; (void)n_in; (void)out_size; (void)ws_size;
    const float* x     = (const float*)d_in[0];
    const float* h0    = (const float*)d_in[1];
    const float* rmean = (const float*)d_in[2];
    const float* rvar  = (const float*)d_in[3];
    const float* wih0  = (const float*)d_in[4];
    const float* wihr  = (const float*)d_in[5];
    const float* whh   = (const float*)d_in[6];
    const float* bih   = (const float*)d_in[7];
    const float* bhh   = (const float*)d_in[8];
    const float* lng   = (const float*)d_in[9];
    const float* lnb   = (const float*)d_in[10];
    float* out = (float*)d_out;
    float* ws  = (float*)d_ws;

    // Plain launches only; no runtime queries (capture-sensitive, r4-r10).
    k_init<<<dim3(4), dim3(1024), 0, stream>>>(ws);
    k_pack<<<dim3(L_*NTILE), dim3(256), 0, stream>>>(wih0, wihr, whh, ws);
    gru_pipe<<<dim3(NBLK), dim3(NTHR), 0, stream>>>(
        x, h0, rmean, rvar, bih, bhh, lng, lnb, out, ws);
}

// Round 15
// 10613.725 us; speedup vs baseline: 2.1436x; 2.1436x over previous
//
#include <hip/hip_runtime.h>
#include <hip/hip_fp16.h>

#define B_   256
#define T_   512
#define D_   200
#define H_   320
#define L_   3
#define G3_  960
#define BH_  (B_*H_)
#define BTH_ (B_*T_*H_)

#define GR_   8              // groups (batch split)
#define RPG_  32             // rows (batch) per group
#define CPB_  48             // output cols per block
#define NCG_  20             // col-groups per layer (960/48)
#define SPG_  60             // blocks per group (3 layers * 20)
#define NP2_  24             // blocks per group owning phase-2 tasks (96/4)
#define NBLK  480            // 2/CU co-residency proven on HW (r7-r13)
#define NTHR  256
#define KIP0  224            // layer-0 input K padded to 32-multiple
#define WSTR  648            // LDS weight row stride in f16 elems

typedef _Float16 half8 __attribute__((ext_vector_type(8)));
typedef float    f32x4 __attribute__((ext_vector_type(4)));
typedef unsigned u32x2 __attribute__((ext_vector_type(2)));

// ---- ws layout (float units) ----
#define OFF_Z     0
#define SZ_Z_F    (L_*B_*G3_/2)            // z as f16
#define OFF_HN    (OFF_Z + SZ_Z_F)
#define SZ_HN_F   (L_*B_*H_/2)             // hn as f16
#define OFF_STF   (OFF_HN + SZ_HN_F)       // f16 hidden state (cross-block)
#define SZ_STF_F  ((L_*BH_)/2)
#define OFF_BAR   (OFF_STF + SZ_STF_F)
// per group: flagsA[60] @0 (spaced 32 words), flagsB[24] @2048
#define FLAG_STR  32
#define FB_OFF    2048
#define GRP_STR   4096
#define BAR_WORDS (GR_*GRP_STR)

__device__ __forceinline__ float sigmoidf_(float v) {
    return 1.0f / (1.0f + __expf(-v));
}

__device__ __forceinline__ float wredsum(float v) {
#pragma unroll
    for (int m = 32; m > 0; m >>= 1) v += __shfl_xor(v, m, 64);
    return v;
}

__device__ __forceinline__ half8 h8zero() {
    half8 a;
#pragma unroll
    for (int j = 0; j < 8; ++j) a[j] = (_Float16)0.f;
    return a;
}

__device__ __forceinline__ unsigned aload(const unsigned* p) {
    return __hip_atomic_load(p, __ATOMIC_RELAXED, __HIP_MEMORY_SCOPE_AGENT);
}
__device__ __forceinline__ void stc(unsigned* p, unsigned v) {
    __hip_atomic_store(p, v, __ATOMIC_RELAXED, __HIP_MEMORY_SCOPE_AGENT);
}

// quad-pack helper: lane-quad (nr,nr+1,nr+2,nr+3) -> u32x2 on quad leader
__device__ __forceinline__ u32x2 quad_pack(float v) {
    unsigned b0 = (unsigned)__builtin_bit_cast(unsigned short, (_Float16)v);
    unsigned b1 = (unsigned)__shfl_xor((int)b0, 1, 64);
    unsigned pr = (b0 & 0xffffu) | (b1 << 16);
    unsigned qr = (unsigned)__shfl_xor((int)pr, 2, 64);
    u32x2 r; r.x = pr; r.y = qr;
    return r;
}
__device__ __forceinline__ void st8c(_Float16* p, u32x2 v) {
    asm volatile("global_store_dwordx2 %0, %1, off sc0 sc1"
                 :: "v"(p), "v"(v) : "memory");
}

// -------- leaderless producer/consumer barriers (1 MALL hop each) ----------
__device__ __forceinline__ void bar_signal(unsigned* flags, int idx, int tid,
                                           unsigned token) {
    __syncthreads();
    if (tid == 0) stc(&flags[idx*FLAG_STR], token);
}
__device__ __forceinline__ void bar_wait(unsigned* flags, int nflags, int tid,
                                         unsigned token) {
    if (tid < 64) {
        for (;;) {
            unsigned v = (tid < nflags) ? aload(&flags[tid*FLAG_STR]) : token;
            if (__all((int)(v - token) >= 0)) break;
            __builtin_amdgcn_s_sleep(1);
        }
    }
    __syncthreads();
}

__device__ __forceinline__ void load_weights(int l, int colbase, int tid,
        const float* __restrict__ wih0, const float* __restrict__ wihr,
        const float* __restrict__ whh,  const float* __restrict__ rmean,
        const float* __restrict__ rvar,
        _Float16 (*w)[WSTR], float (*nrm)[KIP0])
{
    for (int e = tid; e < CPB_*WSTR; e += NTHR) ((_Float16*)w)[e] = (_Float16)0.f;
    if (l == 0) for (int e = tid; e < 2*KIP0; e += NTHR) ((float*)nrm)[e] = 0.f;
    __syncthreads();
    const int KI  = (l == 0) ? D_ : H_;
    const int KIP = (l == 0) ? KIP0 : H_;
    for (int e = tid; e < CPB_*KI; e += NTHR) {
        int c = e / KI, k = e - c*KI;
        float v = (l == 0) ? wih0[(size_t)(colbase + c)*D_ + k]
                           : wihr[((size_t)(l-1)*G3_ + colbase + c)*H_ + k];
        w[c][k] = (_Float16)v;
    }
    for (int e = tid; e < CPB_*H_; e += NTHR) {
        int c = e / H_, k = e - c*H_;
        w[c][KIP + k] = (_Float16)whh[((size_t)l*G3_ + colbase + c)*H_ + k];
    }
    if (l == 0) {
        for (int k = tid; k < D_; k += NTHR) {
            nrm[0][k] = rmean[k];
            nrm[1][k] = rsqrtf(rvar[k] + 1e-8f);
        }
    }
    __syncthreads();
}

template<int KTI, bool L0>
__device__ __forceinline__ void phase1_work(int g, int l, int t, int colbase, int tid,
        const float* __restrict__ x, const _Float16* __restrict__ stf,
        const float* __restrict__ bih, const float* __restrict__ bhh,
        _Float16* __restrict__ zbuf, _Float16* __restrict__ hnbuf,
        const _Float16 (*w)[WSTR], const float (*nrm)[KIP0])
{
    const int wid  = tid >> 6;       // 0 or 1 (caller gates wid<2)
    const int lane = tid & 63;
    const int nr   = lane & 15;
    const int grp  = lane >> 4;
    const int mb   = g*RPG_ + wid*16;
    constexpr int KIP = KTI * 32;

    half8 aI[KTI];
    f32x4 rI[KTI];
    f32x4 rH[10];

    if (L0) {
#pragma unroll
        for (int kt = 0; kt < KTI; ++kt) {
            if (kt == KTI-1 && grp > 0) { aI[kt] = h8zero(); continue; }
            const int k0 = kt*32 + grp*8;
            const float* xr = &x[((size_t)(mb + nr)*T_ + t)*D_ + k0];
            float xv[8];
            *(float4*)&xv[0] = *(const float4*)xr;
            *(float4*)&xv[4] = *(const float4*)(xr + 4);
#pragma unroll
            for (int j = 0; j < 8; ++j) {
                float nv = (xv[j] - nrm[0][k0+j]) * nrm[1][k0+j];
                aI[kt][j] = (_Float16)fminf(fmaxf(nv, -10.f), 10.f);
            }
        }
    } else {
        const _Float16* srcI = &stf[(size_t)(l-1)*BH_ + (size_t)(mb + nr)*H_ + grp*8];
#pragma unroll
        for (int kt = 0; kt < KTI; ++kt)
            asm volatile("global_load_dwordx4 %0, %1, off offset:%2 sc0 sc1"
                         : "=&v"(rI[kt]) : "v"(srcI), "i"(kt*64));
    }
    {
        const _Float16* srcH = &stf[(size_t)l*BH_ + (size_t)(mb + nr)*H_ + grp*8];
#pragma unroll
        for (int kt = 0; kt < 10; ++kt)
            asm volatile("global_load_dwordx4 %0, %1, off offset:%2 sc0 sc1"
                         : "=&v"(rH[kt]) : "v"(srcH), "i"(kt*64));
    }
    asm volatile("s_waitcnt vmcnt(0)" ::: "memory");
    __builtin_amdgcn_sched_barrier(0);
    if (!L0) {
#pragma unroll
        for (int kt = 0; kt < KTI; ++kt) aI[kt] = __builtin_bit_cast(half8, rI[kt]);
    }

    f32x4 accI[3], accH[3];
#pragma unroll
    for (int nt = 0; nt < 3; ++nt) {
#pragma unroll
        for (int r = 0; r < 4; ++r) { accI[nt][r] = 0.f; accH[nt][r] = 0.f; }
    }

#pragma unroll
    for (int kt = 0; kt < KTI; ++kt) {
        const int k0 = kt*32 + grp*8;
#pragma unroll
        for (int nt = 0; nt < 3; ++nt) {
            half8 bf = *(const half8*)&w[nt*16 + nr][k0];
            accI[nt] = __builtin_amdgcn_mfma_f32_16x16x32_f16(aI[kt], bf, accI[nt], 0, 0, 0);
        }
    }
#pragma unroll
    for (int kt = 0; kt < 10; ++kt) {
        const int k0 = kt*32 + grp*8;
        half8 ah = __builtin_bit_cast(half8, rH[kt]);
#pragma unroll
        for (int nt = 0; nt < 3; ++nt) {
            half8 bf = *(const half8*)&w[nt*16 + nr][KIP + k0];
            accH[nt] = __builtin_amdgcn_mfma_f32_16x16x32_f16(ah, bf, accH[nt], 0, 0, 0);
        }
    }

    // ---- store pre-activations: f16, quad-packed 8B coherent stores ----
#pragma unroll
    for (int nt = 0; nt < 3; ++nt) {
        const int col = colbase + nt*16 + nr;
        const float bi = bih[l*G3_ + col];
        const float bh = bhh[l*G3_ + col];
        const bool ru = (colbase + nt*16) < 2*H_;
#pragma unroll
        for (int r = 0; r < 4; ++r) {
            const int m = mb + grp*4 + r;
            float zv = ru ? (accI[nt][r] + accH[nt][r] + bi + bh)
                          : (accI[nt][r] + bi);
            u32x2 zq = quad_pack(zv);
            if ((nr & 3) == 0)
                st8c(&zbuf[((size_t)l*B_ + m)*G3_ + col], zq);
            if (!ru) {
                u32x2 hq = quad_pack(accH[nt][r] + bh);
                if ((nr & 3) == 0)
                    st8c(&hnbuf[((size_t)l*B_ + m)*H_ + (col - 2*H_)], hq);
            }
        }
    }
}

__device__ __forceinline__ void phase1_dispatch(int g, int l, int t, int colbase, int tid,
        const float* x, const _Float16* stf, const float* bih, const float* bhh,
        _Float16* zbuf, _Float16* hnbuf, const _Float16 (*w)[WSTR], const float (*nrm)[KIP0])
{
    if ((tid >> 6) >= 2) return;   // 2 waves of 16 rows cover RPG_=32
    if (l == 0) phase1_work<7,  true >(g, l, t, colbase, tid, x, stf, bih, bhh, zbuf, hnbuf, w, nrm);
    else        phase1_work<10, false>(g, l, t, colbase, tid, x, stf, bih, bhh, zbuf, hnbuf, w, nrm);
}

__device__ __forceinline__ void phase2_work(int g, int tau, int wv, int lane,
        const float* __restrict__ lng, const float* __restrict__ lnb,
        float* hreg, _Float16* __restrict__ stf,
        const _Float16* __restrict__ zbuf, const _Float16* __restrict__ hnbuf,
        float* __restrict__ out)
{
    if (wv >= L_*RPG_) return;            // 96 tasks per group
    const int l2  = wv >> 5;
    const int row = wv & 31;
    const int b2  = g*RPG_ + row;
    const int t2  = tau - l2;
    if (t2 < 0 || t2 >= T_) return;

    const _Float16* zp = zbuf + ((size_t)l2*B_ + b2)*G3_ + (lane & ~3);
    const _Float16* hp = hnbuf + ((size_t)l2*B_ + b2)*H_ + (lane & ~3);
    _Float16*     frow = &stf[(size_t)l2*BH_ + (size_t)b2*H_];

    // quad leaders batch-load 8B units; one waitcnt; shfl-distribute
    u32x2 qz[15], qh[5];
    if ((lane & 3) == 0) {
#pragma unroll
        for (int gi_ = 0; gi_ < 3; ++gi_) {
#pragma unroll
            for (int i = 0; i < 5; ++i)
                asm volatile("global_load_dwordx2 %0, %1, off offset:%2 sc0 sc1"
                             : "=&v"(qz[gi_*5+i]) : "v"(zp), "i"(2*(gi_*320 + i*64)));
        }
#pragma unroll
        for (int i = 0; i < 5; ++i)
            asm volatile("global_load_dwordx2 %0, %1, off offset:%2 sc0 sc1"
                         : "=&v"(qh[i]) : "v"(hp), "i"(2*(i*64)));
    }
    asm volatile("s_waitcnt vmcnt(0)" ::: "memory");
    __builtin_amdgcn_sched_barrier(0);

    const int qlead = lane & ~3;
    float zr[5], zu[5], zn[5], hn[5];
#pragma unroll
    for (int i = 0; i < 5; ++i) {
        u32x2 a0 = qz[i], a1 = qz[5+i], a2 = qz[10+i], a3 = qh[i];
        unsigned x0 = (unsigned)__shfl((int)a0.x, qlead, 64);
        unsigned y0 = (unsigned)__shfl((int)a0.y, qlead, 64);
        unsigned x1 = (unsigned)__shfl((int)a1.x, qlead, 64);
        unsigned y1 = (unsigned)__shfl((int)a1.y, qlead, 64);
        unsigned x2 = (unsigned)__shfl((int)a2.x, qlead, 64);
        unsigned y2 = (unsigned)__shfl((int)a2.y, qlead, 64);
        unsigned x3 = (unsigned)__shfl((int)a3.x, qlead, 64);
        unsigned y3 = (unsigned)__shfl((int)a3.y, qlead, 64);
        unsigned d0 = (lane & 2) ? y0 : x0;
        unsigned d1 = (lane & 2) ? y1 : x1;
        unsigned d2 = (lane & 2) ? y2 : x2;
        unsigned d3 = (lane & 2) ? y3 : x3;
        unsigned h0 = (lane & 1) ? (d0 >> 16) : (d0 & 0xffffu);
        unsigned h1 = (lane & 1) ? (d1 >> 16) : (d1 & 0xffffu);
        unsigned h2 = (lane & 1) ? (d2 >> 16) : (d2 & 0xffffu);
        unsigned h3 = (lane & 1) ? (d3 >> 16) : (d3 & 0xffffu);
        zr[i] = (float)__builtin_bit_cast(_Float16, (unsigned short)h0);
        zu[i] = (float)__builtin_bit_cast(_Float16, (unsigned short)h1);
        zn[i] = (float)__builtin_bit_cast(_Float16, (unsigned short)h2);
        hn[i] = (float)__builtin_bit_cast(_Float16, (unsigned short)h3);
    }

    const float inv320 = 1.0f/320.0f;
    float s  = zr[0]+zr[1]+zr[2]+zr[3]+zr[4];
    float mu = wredsum(s) * inv320;
    float vs = 0.f;
#pragma unroll
    for (int i = 0; i < 5; ++i) { float d = zr[i]-mu; vs += d*d; }
    float inv = rsqrtf(wredsum(vs)*inv320 + 1e-5f);
    float r[5];
#pragma unroll
    for (int i = 0; i < 5; ++i) {
        const int j = lane + i*64;
        r[i] = sigmoidf_((zr[i]-mu)*inv * lng[(l2*3+0)*H_ + j] + lnb[(l2*3+0)*H_ + j]);
    }
    s  = zu[0]+zu[1]+zu[2]+zu[3]+zu[4];
    mu = wredsum(s) * inv320;
    vs = 0.f;
#pragma unroll
    for (int i = 0; i < 5; ++i) { float d = zu[i]-mu; vs += d*d; }
    inv = rsqrtf(wredsum(vs)*inv320 + 1e-5f);
    float u[5];
#pragma unroll
    for (int i = 0; i < 5; ++i) {
        const int j = lane + i*64;
        u[i] = sigmoidf_((zu[i]-mu)*inv * lng[(l2*3+1)*H_ + j] + lnb[(l2*3+1)*H_ + j]);
    }
    float z2[5];
#pragma unroll
    for (int i = 0; i < 5; ++i) z2[i] = zn[i] + r[i]*hn[i];
    s  = z2[0]+z2[1]+z2[2]+z2[3]+z2[4];
    mu = wredsum(s) * inv320;
    vs = 0.f;
#pragma unroll
    for (int i = 0; i < 5; ++i) { float d = z2[i]-mu; vs += d*d; }
    inv = rsqrtf(wredsum(vs)*inv320 + 1e-5f);
#pragma unroll
    for (int i = 0; i < 5; ++i) {
        const int j = lane + i*64;
        float nv = tanhf((z2[i]-mu)*inv * lng[(l2*3+2)*H_ + j] + lnb[(l2*3+2)*H_ + j]);
        float hv = (1.0f - u[i])*nv + u[i]*hreg[i];
        hreg[i] = hv;
        // f16 state: quad-pack -> one 8B coherent store per quad leader
        u32x2 hq = quad_pack(hv);
        if ((lane & 3) == 0) st8c(&frow[j], hq);
        if (l2 == 2)    out[((size_t)b2*T_ + t2)*H_ + j] = hv;   // plain (host-read)
        if (t2 == T_-1) out[(size_t)BTH_ + ((size_t)l2*B_ + b2)*H_ + j] = hv;
    }
}

// ---- init: zero barrier area, init f16 state from h0 ----
__global__ void k_init(const float* __restrict__ h0, float* __restrict__ ws) {
    _Float16*  stf = (_Float16*)(ws + OFF_STF);
    unsigned*  bar = (unsigned*)(ws + OFF_BAR);
    int gt = blockIdx.x*blockDim.x + threadIdx.x;
    for (int i = gt; i < BAR_WORDS; i += gridDim.x*blockDim.x) bar[i] = 0u;
    for (int i = gt; i < L_*BH_; i += gridDim.x*blockDim.x)
        stf[i] = (_Float16)h0[i];
}

// ================= persistent kernel (PLAIN launch, no grid.sync) ===========
__launch_bounds__(NTHR, 2)
__global__ void gru_pers_kernel(const float* __restrict__ x,
                                const float* __restrict__ h0,
                                const float* __restrict__ rmean,
                                const float* __restrict__ rvar,
                                const float* __restrict__ wih0,
                                const float* __restrict__ wihr,
                                const float* __restrict__ whh,
                                const float* __restrict__ bih,
                                const float* __restrict__ bhh,
                                const float* __restrict__ lng,
                                const float* __restrict__ lnb,
                                float* __restrict__ out,
                                float* __restrict__ ws)
{
    _Float16*  zbuf  = (_Float16*)(ws + OFF_Z);
    _Float16*  hnbuf = (_Float16*)(ws + OFF_HN);
    _Float16*  stf   = (_Float16*)(ws + OFF_STF);
    unsigned*  bar   = (unsigned*)(ws + OFF_BAR);

    const int tid = threadIdx.x;
    const int bid = blockIdx.x;
    const int g   = bid & (GR_ - 1);     // any fixed mapping works (MALL-based sync)
    const int idx = bid >> 3;            // 0..59 within group
    const int l   = idx / NCG_;
    const int cgp = idx - l*NCG_;
    const int colbase = cgp * CPB_;
    const bool p2blk = (idx < NP2_);     // this block owns phase-2 tasks

    unsigned* flagsA = bar + g*GRP_STR;
    unsigned* flagsB = bar + g*GRP_STR + FB_OFF;

    __shared__ _Float16 w_lds[CPB_][WSTR];     // 62208 B
    __shared__ float    nrm_lds[2][KIP0];      //  1792 B

    load_weights(l, colbase, tid, wih0, wihr, whh, rmean, rvar, w_lds, nrm_lds);

    const int wid  = tid >> 6;
    const int lane = tid & 63;
    const int wv   = idx*4 + wid;

    // hidden state for this wave's phase-2 task lives in registers
    float hreg[5] = {0.f, 0.f, 0.f, 0.f, 0.f};
    if (wv < L_*RPG_) {
        const int l2 = wv >> 5, row = wv & 31, b2 = g*RPG_ + row;
#pragma unroll
        for (int i = 0; i < 5; ++i)
            hreg[i] = h0[(size_t)l2*BH_ + (size_t)b2*H_ + lane + i*64];
    }

    for (int tau = 0; tau < T_ + L_ - 1; ++tau) {
        const unsigned tok = (unsigned)(tau + 1);
        const int t = tau - l;
        if (t >= 0 && t < T_)
            phase1_dispatch(g, l, t, colbase, tid, x, stf, bih, bhh,
                            zbuf, hnbuf, w_lds, nrm_lds);
        bar_signal(flagsA, idx, tid, tok);          // z of this block is visible
        if (p2blk) {
            bar_wait(flagsA, SPG_, tid, tok);       // all 60 z-producers done
            phase2_work(g, tau, wv, lane, lng, lnb, hreg, stf, zbuf, hnbuf, out);
            bar_signal(flagsB, idx, tid, tok);      // h of this block is visible
        }
        bar_wait(flagsB, NP2_, tid, tok);           // all 24 h-producers done
    }
}

extern "C" void kernel_launch(void* const* d_in, const int* in_sizes, int n_in,
                              void* d_out, int out_size, void* d_ws, size_t ws_size,
                              hipStream_t stream) {
    (void)in_sizes; (void)n_in; (void)out_size; (void)ws_size;
    const float* x     = (const float*)d_in[0];
    const float* h0    = (const float*)d_in[1];
    const float* rmean = (const float*)d_in[2];
    const float* rvar  = (const float*)d_in[3];
    const float* wih0  = (const float*)d_in[4];
    const float* wihr  = (const float*)d_in[5];
    const float* whh   = (const float*)d_in[6];
    const float* bih   = (const float*)d_in[7];
    const float* bhh   = (const float*)d_in[8];
    const float* lng   = (const float*)d_in[9];
    const float* lnb   = (const float*)d_in[10];
    float* out = (float*)d_out;
    float* ws  = (float*)d_ws;

    // Plain launches only (coop rejected in r9/r10); no runtime queries.
    k_init<<<dim3(240), dim3(NTHR), 0, stream>>>(h0, ws);
    gru_pers_kernel<<<dim3(NBLK), dim3(NTHR), 0, stream>>>(
        x, h0, rmean, rvar, wih0, wihr, whh, bih, bhh, lng, lnb, out, ws);
}

// Round 16
// 5163.316 us; speedup vs baseline: 4.4065x; 2.0556x over previous
//
#include <hip/hip_runtime.h>
#include <hip/hip_fp16.h>

#define B_   256
#define T_   512
#define D_   200
#define H_   320
#define L_   3
#define G3_  960
#define BH_  (B_*H_)
#define BTH_ (B_*T_*H_)

#define GR_   8              // groups = XCDs
#define RPG_  32             // rows (batch) per group
#define CPB_  48             // output cols per block
#define NCG_  20             // col-groups per layer (960/48)
#define SPG_  60             // workers per group (3 layers * 20)
#define NP2_  24             // workers owning phase-2 tasks (96/4)
#define NBLK  512            // 2/CU fill -> ~64 blocks/XCD -> each group fills
#define NTHR  256
#define KIP0  224            // layer-0 input K padded to 32-multiple
#define WSTR  648            // LDS weight row stride in f16 elems

typedef _Float16 half8 __attribute__((ext_vector_type(8)));
typedef float    f32x4 __attribute__((ext_vector_type(4)));

// ---- ws layout (float units) ----
#define OFF_Z     0
#define SZ_Z      (L_*B_*G3_)
#define OFF_HN    (OFF_Z + SZ_Z)
#define SZ_HN     (L_*B_*H_)
#define OFF_STF   (OFF_HN + SZ_HN)
#define SZ_STF_F  ((L_*BH_)/2)
#define OFF_BAR   (OFF_STF + SZ_STF_F)
// per group: flagsA[60] @0 (spaced 32 words), flagsB[24] @FB_OFF; tickets after
#define FLAG_STR  32
#define FB_OFF    2048
#define GRP_STR   4096
#define TCK_OFF   (GR_*GRP_STR)
#define BAR_WORDS (GR_*GRP_STR + 256)

__device__ __forceinline__ float sigmoidf_(float v) {
    return 1.0f / (1.0f + __expf(-v));
}

__device__ __forceinline__ float wredsum(float v) {
#pragma unroll
    for (int m = 32; m > 0; m >>= 1) v += __shfl_xor(v, m, 64);
    return v;
}

__device__ __forceinline__ half8 h8zero() {
    half8 a;
#pragma unroll
    for (int j = 0; j < 8; ++j) a[j] = (_Float16)0.f;
    return a;
}

// L2-local (workgroup-scope) flag helpers: same-XCD blocks share the L2, so
// these never touch the far coherence point.
__device__ __forceinline__ void l2st(unsigned* p, unsigned v) {
    __hip_atomic_store(p, v, __ATOMIC_RELAXED, __HIP_MEMORY_SCOPE_WORKGROUP);
}
__device__ __forceinline__ unsigned l2ticket(unsigned* p) {
    return __hip_atomic_fetch_add(p, 1u, __ATOMIC_RELAXED, __HIP_MEMORY_SCOPE_WORKGROUP);
}

// -------- leaderless producer/consumer barriers (XCD-local, plain data) -----
// signal: __syncthreads drains vmcnt (write-through stores now in local L2),
// then one flag store. wait: wave-0 polls producer flags with per-iteration
// vL1 invalidate (buffer_inv = CU-local, no fabric traffic) + volatile loads;
// closing buffer_inv makes every wave's subsequent plain loads L2-fresh.
__device__ __forceinline__ void bar_signal(unsigned* flags, int idx, int tid,
                                           unsigned token) {
    __syncthreads();
    if (tid == 0) l2st(&flags[idx*FLAG_STR], token);
}
__device__ __forceinline__ void bar_wait(unsigned* flags, int nflags, int tid,
                                         unsigned token) {
    if (tid < 64) {
        for (;;) {
            asm volatile("buffer_inv" ::: "memory");
            unsigned v = token;
            if (tid < nflags) v = ((volatile unsigned*)flags)[tid*FLAG_STR];
            if (__all((int)(v - token) >= 0)) break;
            __builtin_amdgcn_s_sleep(1);
        }
    }
    __syncthreads();
    asm volatile("buffer_inv" ::: "memory");
}

__device__ __forceinline__ void load_weights(int l, int colbase, int tid,
        const float* __restrict__ wih0, const float* __restrict__ wihr,
        const float* __restrict__ whh,  const float* __restrict__ rmean,
        const float* __restrict__ rvar,
        _Float16 (*w)[WSTR], float (*nrm)[KIP0])
{
    for (int e = tid; e < CPB_*WSTR; e += NTHR) ((_Float16*)w)[e] = (_Float16)0.f;
    if (l == 0) for (int e = tid; e < 2*KIP0; e += NTHR) ((float*)nrm)[e] = 0.f;
    __syncthreads();
    const int KI  = (l == 0) ? D_ : H_;
    const int KIP = (l == 0) ? KIP0 : H_;
    for (int e = tid; e < CPB_*KI; e += NTHR) {
        int c = e / KI, k = e - c*KI;
        float v = (l == 0) ? wih0[(size_t)(colbase + c)*D_ + k]
                           : wihr[((size_t)(l-1)*G3_ + colbase + c)*H_ + k];
        w[c][k] = (_Float16)v;
    }
    for (int e = tid; e < CPB_*H_; e += NTHR) {
        int c = e / H_, k = e - c*H_;
        w[c][KIP + k] = (_Float16)whh[((size_t)l*G3_ + colbase + c)*H_ + k];
    }
    if (l == 0) {
        for (int k = tid; k < D_; k += NTHR) {
            nrm[0][k] = rmean[k];
            nrm[1][k] = rsqrtf(rvar[k] + 1e-8f);
        }
    }
    __syncthreads();
}

template<int KTI, bool L0>
__device__ __forceinline__ void phase1_work(int g, int l, int t, int colbase, int tid,
        const float* __restrict__ x, const _Float16* __restrict__ stf,
        const float* __restrict__ bih, const float* __restrict__ bhh,
        float* __restrict__ zbuf, float* __restrict__ hnbuf,
        const _Float16 (*w)[WSTR], const float (*nrm)[KIP0])
{
    const int wid  = tid >> 6;       // 0 or 1 (caller gates wid<2)
    const int lane = tid & 63;
    const int nr   = lane & 15;
    const int grp  = lane >> 4;
    const int mb   = g*RPG_ + wid*16;
    constexpr int KIP = KTI * 32;

    // plain cached loads (fresh: buffer_inv ran at barrier exit; data in local L2)
    half8 aI[KTI];
    if (L0) {
#pragma unroll
        for (int kt = 0; kt < KTI; ++kt) {
            if (kt == KTI-1 && grp > 0) { aI[kt] = h8zero(); continue; }
            const int k0 = kt*32 + grp*8;
            const float* xr = &x[((size_t)(mb + nr)*T_ + t)*D_ + k0];
            float xv[8];
            *(float4*)&xv[0] = *(const float4*)xr;
            *(float4*)&xv[4] = *(const float4*)(xr + 4);
#pragma unroll
            for (int j = 0; j < 8; ++j) {
                float nv = (xv[j] - nrm[0][k0+j]) * nrm[1][k0+j];
                aI[kt][j] = (_Float16)fminf(fmaxf(nv, -10.f), 10.f);
            }
        }
    } else {
        const _Float16* srcI = &stf[(size_t)(l-1)*BH_ + (size_t)(mb + nr)*H_ + grp*8];
#pragma unroll
        for (int kt = 0; kt < KTI; ++kt) aI[kt] = *(const half8*)(srcI + kt*32);
    }
    half8 aH[10];
    {
        const _Float16* srcH = &stf[(size_t)l*BH_ + (size_t)(mb + nr)*H_ + grp*8];
#pragma unroll
        for (int kt = 0; kt < 10; ++kt) aH[kt] = *(const half8*)(srcH + kt*32);
    }

    f32x4 accI[3], accH[3];
#pragma unroll
    for (int nt = 0; nt < 3; ++nt) {
#pragma unroll
        for (int r = 0; r < 4; ++r) { accI[nt][r] = 0.f; accH[nt][r] = 0.f; }
    }

#pragma unroll
    for (int kt = 0; kt < KTI; ++kt) {
        const int k0 = kt*32 + grp*8;
#pragma unroll
        for (int nt = 0; nt < 3; ++nt) {
            half8 bf = *(const half8*)&w[nt*16 + nr][k0];
            accI[nt] = __builtin_amdgcn_mfma_f32_16x16x32_f16(aI[kt], bf, accI[nt], 0, 0, 0);
        }
    }
#pragma unroll
    for (int kt = 0; kt < 10; ++kt) {
        const int k0 = kt*32 + grp*8;
#pragma unroll
        for (int nt = 0; nt < 3; ++nt) {
            half8 bf = *(const half8*)&w[nt*16 + nr][KIP + k0];
            accH[nt] = __builtin_amdgcn_mfma_f32_16x16x32_f16(aH[kt], bf, accH[nt], 0, 0, 0);
        }
    }

    // ---- store pre-activations: plain write-through stores (land in local L2)
#pragma unroll
    for (int nt = 0; nt < 3; ++nt) {
        const int col = colbase + nt*16 + nr;
        const float bi = bih[l*G3_ + col];
        const float bh = bhh[l*G3_ + col];
        const bool ru = (colbase + nt*16) < 2*H_;
#pragma unroll
        for (int r = 0; r < 4; ++r) {
            const int m = mb + grp*4 + r;
            const size_t zi = ((size_t)l*B_ + m)*G3_ + col;
            if (ru) {
                zbuf[zi] = accI[nt][r] + accH[nt][r] + bi + bh;
            } else {
                zbuf[zi] = accI[nt][r] + bi;
                hnbuf[((size_t)l*B_ + m)*H_ + (col - 2*H_)] = accH[nt][r] + bh;
            }
        }
    }
}

__device__ __forceinline__ void phase1_dispatch(int g, int l, int t, int colbase, int tid,
        const float* x, const _Float16* stf, const float* bih, const float* bhh,
        float* zbuf, float* hnbuf, const _Float16 (*w)[WSTR], const float (*nrm)[KIP0])
{
    if ((tid >> 6) >= 2) return;   // 2 waves of 16 rows cover RPG_=32
    if (l == 0) phase1_work<7,  true >(g, l, t, colbase, tid, x, stf, bih, bhh, zbuf, hnbuf, w, nrm);
    else        phase1_work<10, false>(g, l, t, colbase, tid, x, stf, bih, bhh, zbuf, hnbuf, w, nrm);
}

__device__ __forceinline__ void phase2_work(int g, int tau, int wv, int lane,
        const float* __restrict__ lng, const float* __restrict__ lnb,
        float* hreg, _Float16* __restrict__ stf,
        const float* __restrict__ zbuf, const float* __restrict__ hnbuf,
        float* __restrict__ out)
{
    if (wv >= L_*RPG_) return;            // 96 tasks per group
    const int l2  = wv >> 5;
    const int row = wv & 31;
    const int b2  = g*RPG_ + row;
    const int t2  = tau - l2;
    if (t2 < 0 || t2 >= T_) return;

    const float* zrow  = &zbuf[((size_t)l2*B_ + b2)*G3_];
    const float* hnrow = &hnbuf[((size_t)l2*B_ + b2)*H_];
    _Float16*    frow  = &stf[(size_t)l2*BH_ + (size_t)b2*H_];

    float zr[5], zu[5], zn[5], hn[5];
#pragma unroll
    for (int i = 0; i < 5; ++i) {
        const int j = lane + i*64;
        zr[i] = zrow[j];
        zu[i] = zrow[320 + j];
        zn[i] = zrow[640 + j];
        hn[i] = hnrow[j];
    }
    const float inv320 = 1.0f/320.0f;
    float s  = zr[0]+zr[1]+zr[2]+zr[3]+zr[4];
    float mu = wredsum(s) * inv320;
    float vs = 0.f;
#pragma unroll
    for (int i = 0; i < 5; ++i) { float d = zr[i]-mu; vs += d*d; }
    float inv = rsqrtf(wredsum(vs)*inv320 + 1e-5f);
    float r[5];
#pragma unroll
    for (int i = 0; i < 5; ++i) {
        const int j = lane + i*64;
        r[i] = sigmoidf_((zr[i]-mu)*inv * lng[(l2*3+0)*H_ + j] + lnb[(l2*3+0)*H_ + j]);
    }
    s  = zu[0]+zu[1]+zu[2]+zu[3]+zu[4];
    mu = wredsum(s) * inv320;
    vs = 0.f;
#pragma unroll
    for (int i = 0; i < 5; ++i) { float d = zu[i]-mu; vs += d*d; }
    inv = rsqrtf(wredsum(vs)*inv320 + 1e-5f);
    float u[5];
#pragma unroll
    for (int i = 0; i < 5; ++i) {
        const int j = lane + i*64;
        u[i] = sigmoidf_((zu[i]-mu)*inv * lng[(l2*3+1)*H_ + j] + lnb[(l2*3+1)*H_ + j]);
    }
    float z2[5];
#pragma unroll
    for (int i = 0; i < 5; ++i) z2[i] = zn[i] + r[i]*hn[i];
    s  = z2[0]+z2[1]+z2[2]+z2[3]+z2[4];
    mu = wredsum(s) * inv320;
    vs = 0.f;
#pragma unroll
    for (int i = 0; i < 5; ++i) { float d = z2[i]-mu; vs += d*d; }
    inv = rsqrtf(wredsum(vs)*inv320 + 1e-5f);
#pragma unroll
    for (int i = 0; i < 5; ++i) {
        const int j = lane + i*64;
        float nv = tanhf((z2[i]-mu)*inv * lng[(l2*3+2)*H_ + j] + lnb[(l2*3+2)*H_ + j]);
        float hv = (1.0f - u[i])*nv + u[i]*hreg[i];
        hreg[i] = hv;
        // f16 state: pair adjacent lanes -> one plain 4B store per even lane
        unsigned hb = (unsigned)__builtin_bit_cast(unsigned short, (_Float16)hv);
        unsigned ob = (unsigned)__shfl_xor((int)hb, 1, 64);
        if ((lane & 1) == 0)
            ((unsigned*)frow)[j >> 1] = (hb & 0xffffu) | (ob << 16);
        if (l2 == 2)    out[((size_t)b2*T_ + t2)*H_ + j] = hv;
        if (t2 == T_-1) out[(size_t)BTH_ + ((size_t)l2*B_ + b2)*H_ + j] = hv;
    }
}

// ---- init: zero barrier+ticket area, init f16 state from h0 ----
__global__ void k_init(const float* __restrict__ h0, float* __restrict__ ws) {
    _Float16*  stf = (_Float16*)(ws + OFF_STF);
    unsigned*  bar = (unsigned*)(ws + OFF_BAR);
    int gt = blockIdx.x*blockDim.x + threadIdx.x;
    for (int i = gt; i < BAR_WORDS; i += gridDim.x*blockDim.x) bar[i] = 0u;
    for (int i = gt; i < L_*BH_; i += gridDim.x*blockDim.x)
        stf[i] = (_Float16)h0[i];
}

// ================= persistent kernel (plain launch, XCD-local groups) =======
// Each block reads its physical XCC_ID and takes a ticket from its XCD's
// counter: slot<60 -> worker (group = XCD, idx = slot); slot>=60 -> exit.
// All group traffic (z, hn, stf, flags) stays in the XCD's L2: plain
// write-through stores + buffer_inv(vL1) on consume. Late-scheduled blocks
// self-heal: members block on monotonic tokens until the worker joins.
__launch_bounds__(NTHR, 2)
__global__ void gru_pers_kernel(const float* __restrict__ x,
                                const float* __restrict__ h0,
                                const float* __restrict__ rmean,
                                const float* __restrict__ rvar,
                                const float* __restrict__ wih0,
                                const float* __restrict__ wihr,
                                const float* __restrict__ whh,
                                const float* __restrict__ bih,
                                const float* __restrict__ bhh,
                                const float* __restrict__ lng,
                                const float* __restrict__ lnb,
                                float* __restrict__ out,
                                float* __restrict__ ws)
{
    float*     zbuf  = ws + OFF_Z;
    float*     hnbuf = ws + OFF_HN;
    _Float16*  stf   = (_Float16*)(ws + OFF_STF);
    unsigned*  bar   = (unsigned*)(ws + OFF_BAR);

    const int tid = threadIdx.x;

    // ---- ticket-based XCD-local group formation ----
    unsigned myxcd;
    asm volatile("s_getreg_b32 %0, hwreg(HW_REG_XCC_ID)" : "=s"(myxcd));
    myxcd &= 7u;
    __shared__ unsigned sh_slot;
    if (tid == 0) sh_slot = l2ticket(&bar[TCK_OFF + myxcd*32]);
    __syncthreads();
    const unsigned slot = sh_slot;
    if (slot >= (unsigned)SPG_) return;      // surplus block: free the CU slot

    const int g   = (int)myxcd;
    const int idx = (int)slot;
    const int l   = idx / NCG_;
    const int cgp = idx - l*NCG_;
    const int colbase = cgp * CPB_;
    const bool p2blk = (idx < NP2_);

    unsigned* flagsA = bar + g*GRP_STR;
    unsigned* flagsB = bar + g*GRP_STR + FB_OFF;

    __shared__ _Float16 w_lds[CPB_][WSTR];     // 62208 B
    __shared__ float    nrm_lds[2][KIP0];      //  1792 B

    load_weights(l, colbase, tid, wih0, wihr, whh, rmean, rvar, w_lds, nrm_lds);

    const int wid  = tid >> 6;
    const int lane = tid & 63;
    const int wv   = idx*4 + wid;

    float hreg[5] = {0.f, 0.f, 0.f, 0.f, 0.f};
    if (wv < L_*RPG_) {
        const int l2 = wv >> 5, row = wv & 31, b2 = g*RPG_ + row;
#pragma unroll
        for (int i = 0; i < 5; ++i)
            hreg[i] = h0[(size_t)l2*BH_ + (size_t)b2*H_ + lane + i*64];
    }

    for (int tau = 0; tau < T_ + L_ - 1; ++tau) {
        const unsigned tok = (unsigned)(tau + 1);
        const int t = tau - l;
        if (t >= 0 && t < T_)
            phase1_dispatch(g, l, t, colbase, tid, x, stf, bih, bhh,
                            zbuf, hnbuf, w_lds, nrm_lds);
        bar_signal(flagsA, idx, tid, tok);          // z of this block in L2
        if (p2blk) {
            bar_wait(flagsA, SPG_, tid, tok);       // all 60 z-producers done
            phase2_work(g, tau, wv, lane, lng, lnb, hreg, stf, zbuf, hnbuf, out);
            bar_signal(flagsB, idx, tid, tok);      // h of this block in L2
        }
        bar_wait(flagsB, NP2_, tid, tok);           // all 24 h-producers done
    }
}

extern "C" void kernel_launch(void* const* d_in, const int* in_sizes, int n_in,
                              void* d_out, int out_size, void* d_ws, size_t ws_size,
                              hipStream_t stream) {
    (void)in_sizes; (void)n_in; (void)out_size; (void)ws_size;
    const float* x     = (const float*)d_in[0];
    const float* h0    = (const float*)d_in[1];
    const float* rmean = (const float*)d_in[2];
    const float* rvar  = (const float*)d_in[3];
    const float* wih0  = (const float*)d_in[4];
    const float* wihr  = (const float*)d_in[5];
    const float* whh   = (const float*)d_in[6];
    const float* bih   = (const float*)d_in[7];
    const float* bhh   = (const float*)d_in[8];
    const float* lng   = (const float*)d_in[9];
    const float* lnb   = (const float*)d_in[10];
    float* out = (float*)d_out;
    float* ws  = (float*)d_ws;

    // Plain launches only (coop rejected in r9/r10); no runtime queries.
    k_init<<<dim3(240), dim3(NTHR), 0, stream>>>(h0, ws);
    gru_pers_kernel<<<dim3(NBLK), dim3(NTHR), 0, stream>>>(
        x, h0, rmean, rvar, wih0, wihr, whh, bih, bhh, lng, lnb, out, ws);
}